// Round 17
// baseline (611.647 us; speedup 1.0000x reference)
//
#include <hip/hip_runtime.h>
#include <hip/hip_bf16.h>

// ---------- types ----------
typedef short bf16x8 __attribute__((ext_vector_type(8)));   // 8 bf16 (4 VGPRs)
typedef float f32x4  __attribute__((ext_vector_type(4)));

typedef __attribute__((address_space(1))) const unsigned int gu32_t;
typedef __attribute__((address_space(3))) unsigned int lu32_t;

__device__ inline void gld16(const void* g, void* l) {
  // async global->LDS, 16B per lane; dest must be wave-uniform-base + lane*16
  __builtin_amdgcn_global_load_lds((gu32_t*)g, (lu32_t*)l, 16, 0, 0);
}

__device__ inline float bf2f(__hip_bfloat16 x) { return __bfloat162float(x); }

#define S_LEN 2048
#define HID   4096
#define NH    32
#define HD    128
#define QKV_N 12288

// ---------- fp32 -> bf16 convert (vectorized, grid-stride) ----------
__global__ void cvt_bf16_kernel(const float* __restrict__ in,
                                __hip_bfloat16* __restrict__ out, long n) {
  long stride = (long)gridDim.x * blockDim.x;
  for (long i = (long)blockIdx.x * blockDim.x + threadIdx.x; i * 8 < n; i += stride) {
    long b = i * 8;
    float4 a0 = *(const float4*)(in + b);
    float4 a1 = *(const float4*)(in + b + 4);
    union { __hip_bfloat16 h[8]; bf16x8 v; } u;
    u.h[0] = __float2bfloat16(a0.x); u.h[1] = __float2bfloat16(a0.y);
    u.h[2] = __float2bfloat16(a0.z); u.h[3] = __float2bfloat16(a0.w);
    u.h[4] = __float2bfloat16(a1.x); u.h[5] = __float2bfloat16(a1.y);
    u.h[6] = __float2bfloat16(a1.z); u.h[7] = __float2bfloat16(a1.w);
    *(bf16x8*)(out + b) = u.v;
  }
}

// ---------- GEMM: 256x128 block, 4 waves x (128x64), 16x16x32 MFMA ----------
// ROUND 17: bigger per-wave tile at the CONFLICT-FREE row-period-16 read
// pattern. R16's 32x32 (row = lane&31 reads) measured 2.5e7 bank-conflict
// cycles vs exactly 0 for the 16x16 pattern (row = lane&15); empirical rule:
// keep row-period-16. Per wave-K-step: 24 LDS reads for 64 MFMA (was 16/32)
// -> LDS bytes/FLOP -25%; staging bytes/FLOP -43% (48KB tile, 2x FLOPs).
// acc[8][4] f32x4 = 128 VGPR -> ~200 total, 2 waves/SIMD, 2 blocks/CU.
// T1 XCD chunk swizzle + T2 source/read XOR swizzle (rule #21) unchanged.
// Inner loop keeps af transient (1 live A-frag) to cap VGPR.
template<int WRITE_BF16>
__global__ __launch_bounds__(256) void gemm_bt_kernel(
    const __hip_bfloat16* __restrict__ A,
    const __hip_bfloat16* __restrict__ B,
    const float* __restrict__ bias,
    void* __restrict__ Cout, int M, int N, int K)
{
  __shared__ __hip_bfloat16 lA[256 * 64];   // 32KB
  __shared__ __hip_bfloat16 lB[128 * 64];   // 16KB
  const int t = threadIdx.x;
  const int w = t >> 6, l = t & 63;
  const int lr = l & 15, lg = l >> 4;
  const int nwg = gridDim.x * gridDim.y;
  const int bid = blockIdx.y * gridDim.x + blockIdx.x;
  const int swz = (bid & 7) * (nwg >> 3) + (bid >> 3);   // XCD chunk swizzle
  const int m0 = (swz % gridDim.x) * 256, n0 = (swz / gridDim.x) * 128;
  const int wr = w >> 1, wc = w & 1;        // wave: rows wr*128, cols wc*64

  f32x4 acc[8][4] = {};

  for (int k0 = 0; k0 < K; k0 += 64) {
    #pragma unroll
    for (int i = 0; i < 8; ++i) {           // A tile: 256 rows x 8 slots
      int c = i * 256 + t;
      int row = c >> 3, s = c & 7;          // source slot pre-swizzled
      gld16(A + (long)(m0 + row) * K + k0 + (s ^ (row & 7)) * 8, &lA[c * 8]);
    }
    #pragma unroll
    for (int i = 0; i < 4; ++i) {           // B tile: 128 rows x 8 slots
      int c = i * 256 + t;
      int row = c >> 3, s = c & 7;
      gld16(B + (long)(n0 + row) * K + k0 + (s ^ (row & 7)) * 8, &lB[c * 8]);
    }
    __syncthreads();                        // drains vmcnt before barrier
    #pragma unroll
    for (int ks = 0; ks < 2; ++ks) {
      bf16x8 bfr[4];
      #pragma unroll
      for (int ni = 0; ni < 4; ++ni) {
        int row = wc * 64 + ni * 16 + lr;
        bfr[ni] = *(const bf16x8*)&lB[row * 64 + ((ks * 4 + lg) ^ (row & 7)) * 8];
      }
      #pragma unroll
      for (int mi = 0; mi < 8; ++mi) {
        int row = wr * 128 + mi * 16 + lr;
        bf16x8 af = *(const bf16x8*)&lA[row * 64 + ((ks * 4 + lg) ^ (row & 7)) * 8];
        #pragma unroll
        for (int ni = 0; ni < 4; ++ni)
          acc[mi][ni] = __builtin_amdgcn_mfma_f32_16x16x32_bf16(af, bfr[ni], acc[mi][ni], 0, 0, 0);
      }
    }
    __syncthreads();
  }

  #pragma unroll
  for (int mi = 0; mi < 8; ++mi) {
    #pragma unroll
    for (int ni = 0; ni < 4; ++ni) {
      int col = n0 + wc * 64 + ni * 16 + lr;
      float bv = bias[col];
      #pragma unroll
      for (int r = 0; r < 4; ++r) {
        int row = m0 + wr * 128 + mi * 16 + lg * 4 + r;  // C/D: col=lane&15, row=(lane>>4)*4+reg
        float v = acc[mi][ni][r] + bv;
        if (WRITE_BF16)
          ((__hip_bfloat16*)Cout)[(long)row * N + col] = __float2bfloat16(v);
        else
          ((float*)Cout)[(long)row * N + col] = v;
      }
    }
  }
}

// ---------- RoPE cos/sin table: [s][64] ----------
__global__ void rope_table_kernel(const int* __restrict__ pos,
                                  float* __restrict__ ct, float* __restrict__ st) {
  int s = blockIdx.x, j = threadIdx.x;      // 2048 x 64
  float p = (float)pos[s];
  float invf = exp2f(-0.20762050593046013f * (float)j);
  float a = p * invf;
  ct[s * 64 + j] = cosf(a);
  st[s * 64 + j] = sinf(a);
}

// ---------- RoPE + rearrange (vectorized, R13) ----------
__global__ __launch_bounds__(256) void rope_rearrange_kernel(
    const __hip_bfloat16* __restrict__ qkv,
    const float* __restrict__ ct, const float* __restrict__ st,
    __hip_bfloat16* __restrict__ Qr, __hip_bfloat16* __restrict__ Kr,
    __hip_bfloat16* __restrict__ Vt)
{
  __shared__ __hip_bfloat16 lv[64][136];    // padded to break bank conflicts on transpose read
  const int h = blockIdx.y, s0 = blockIdx.x * 64, t = threadIdx.x;

  #pragma unroll
  for (int half = 0; half < 2; ++half) {
    int si = half * 32 + (t >> 3);          // row within tile
    int jo = (t & 7) * 8;                   // 8 consecutive j per lane
    long base = (long)(s0 + si) * QKV_N + h * 384;
    union { __hip_bfloat16 h8[8]; bf16x8 v; } q1, q2, k1, k2, o;
    q1.v = *(const bf16x8*)(qkv + base + jo);
    q2.v = *(const bf16x8*)(qkv + base + 64 + jo);
    k1.v = *(const bf16x8*)(qkv + base + 128 + jo);
    k2.v = *(const bf16x8*)(qkv + base + 192 + jo);
    const float* cp = ct + (s0 + si) * 64 + jo;
    const float* sp = st + (s0 + si) * 64 + jo;
    long ob = (long)h * (S_LEN * HD) + (long)(s0 + si) * HD;
    #pragma unroll
    for (int e = 0; e < 8; ++e)
      o.h8[e] = __float2bfloat16(bf2f(q1.h8[e]) * cp[e] - bf2f(q2.h8[e]) * sp[e]);
    *(bf16x8*)(Qr + ob + jo) = o.v;
    #pragma unroll
    for (int e = 0; e < 8; ++e)
      o.h8[e] = __float2bfloat16(bf2f(q2.h8[e]) * cp[e] + bf2f(q1.h8[e]) * sp[e]);
    *(bf16x8*)(Qr + ob + 64 + jo) = o.v;
    #pragma unroll
    for (int e = 0; e < 8; ++e)
      o.h8[e] = __float2bfloat16(bf2f(k1.h8[e]) * cp[e] - bf2f(k2.h8[e]) * sp[e]);
    *(bf16x8*)(Kr + ob + jo) = o.v;
    #pragma unroll
    for (int e = 0; e < 8; ++e)
      o.h8[e] = __float2bfloat16(bf2f(k2.h8[e]) * cp[e] + bf2f(k1.h8[e]) * sp[e]);
    *(bf16x8*)(Kr + ob + 64 + jo) = o.v;
    *(bf16x8*)&lv[si][jo]      = *(const bf16x8*)(qkv + base + 256 + jo);
    *(bf16x8*)&lv[si][64 + jo] = *(const bf16x8*)(qkv + base + 320 + jo);
  }
  __syncthreads();
  #pragma unroll
  for (int i = 0; i < 4; ++i) {
    int c = i * 256 + t;                    // 128 d x 8 chunks of 8 s
    int d = c >> 3, s8 = (c & 7) * 8;
    union { __hip_bfloat16 h8[8]; bf16x8 v; } u;
    #pragma unroll
    for (int j2 = 0; j2 < 8; ++j2) u.h8[j2] = lv[s8 + j2][d];
    *(bf16x8*)(Vt + (long)h * (HD * S_LEN) + (long)d * S_LEN + s0 + s8) = u.v;
  }
}

// ---------- causal flash attention (R15 config: frozen) ----------
// QBLK=64, paired q-tiles {p, 31-p} -> 33 k-tiles/block uniform, grid 16x32.
// K/V dbuf; log2 softmax, diagonal-only mask, T13 defer-max; T5 setprio.
// lK: 16 slots/row swizzle row&15; lV: 8 slots/row swizzle row&7 (T2).
#define FA_STAGE(buf, k0_) do {                                              \
    _Pragma("unroll")                                                        \
    for (int i_ = 0; i_ < 4; ++i_) {       /* K tile: 64 k x 128 d */        \
      int c_ = i_ * 256 + t;                                                 \
      int row_ = c_ >> 4, s_ = c_ & 15;                                      \
      gld16(Kh + (long)((k0_) + row_) * HD + (s_ ^ (row_ & 15)) * 8,         \
            &lK[buf][c_ * 8]);                                               \
    }                                                                        \
    _Pragma("unroll")                                                        \
    for (int i_ = 0; i_ < 4; ++i_) {       /* V^T tile: 128 d x 64 k */      \
      int c_ = i_ * 256 + t;                                                 \
      int d_ = c_ >> 3, s_ = c_ & 7;                                         \
      gld16(Vh + (long)d_ * S_LEN + (k0_) + (s_ ^ (d_ & 7)) * 8,             \
            &lV[buf][c_ * 8]);                                               \
    } } while (0)

__global__ __launch_bounds__(256) void flash_attn_kernel(
    const __hip_bfloat16* __restrict__ Qr, const __hip_bfloat16* __restrict__ Kr,
    const __hip_bfloat16* __restrict__ Vt, __hip_bfloat16* __restrict__ O)
{
  __shared__ __hip_bfloat16 lK[2][64 * 128];   // 2 x 16KB
  __shared__ __hip_bfloat16 lV[2][128 * 64];   // 2 x 16KB
  __shared__ __hip_bfloat16 lP[4][16 * 72];    // per-wave P, padded stride
  const int h = blockIdx.y, pair = blockIdx.x;
  const int t = threadIdx.x, w = t >> 6, l = t & 63;
  const int lr = l & 15, lg = l >> 4;
  const __hip_bfloat16* Qh = Qr + (long)h * (S_LEN * HD);
  const __hip_bfloat16* Kh = Kr + (long)h * (S_LEN * HD);
  const __hip_bfloat16* Vh = Vt + (long)h * (HD * S_LEN);
  const float sc2 = 0.12751744f;            // (1/sqrt(128)) * log2(e)

  for (int ph = 0; ph < 2; ++ph) {
    const int qt = ph ? (31 - pair) : pair;
    const int q0 = qt * 64;

    // hoist this q-tile's Q fragments to registers
    bf16x8 qf[4];
    #pragma unroll
    for (int ks = 0; ks < 4; ++ks)
      qf[ks] = *(const bf16x8*)(Qh + (long)(q0 + w * 16 + lr) * HD + ks * 32 + lg * 8);

    float m_r[4], l_r[4];
    f32x4 oacc[8] = {};
    #pragma unroll
    for (int r = 0; r < 4; ++r) { m_r[r] = -1e30f; l_r[r] = 0.f; }

    const int ktiles = qt + 1;              // causal: k <= q0+63
    int cur = 0;
    FA_STAGE(0, 0);                         // prologue: tile 0 -> buf0
    __syncthreads();                        // drains vmcnt(0)

    for (int kt = 0; kt < ktiles; ++kt) {
      const int k0 = kt * 64;
      if (kt + 1 < ktiles) FA_STAGE(cur ^ 1, k0 + 64);   // overlap with compute

      // S = Q K^T (one 16-row m-frag per wave), setprio around MFMA cluster
      f32x4 s[4] = {};
      #pragma unroll
      for (int ks = 0; ks < 4; ++ks) {
        bf16x8 kf[4];
        #pragma unroll
        for (int nf = 0; nf < 4; ++nf) {
          int row = nf * 16 + lr;
          kf[nf] = *(const bf16x8*)&lK[cur][row * 128 + ((ks * 4 + lg) ^ (row & 15)) * 8];
        }
        __builtin_amdgcn_s_setprio(1);
        #pragma unroll
        for (int nf = 0; nf < 4; ++nf)
          s[nf] = __builtin_amdgcn_mfma_f32_16x16x32_bf16(qf[ks], kf[nf], s[nf], 0, 0, 0);
        __builtin_amdgcn_s_setprio(0);
      }

      // scale to log2 domain; causal mask only on the diagonal tile
      if (kt == qt) {
        #pragma unroll
        for (int nf = 0; nf < 4; ++nf) {
          int k = k0 + nf * 16 + lr;
          #pragma unroll
          for (int r = 0; r < 4; ++r) {
            int q = q0 + w * 16 + lg * 4 + r;
            float v = s[nf][r] * sc2;
            s[nf][r] = (k > q) ? -1e30f : v;
          }
        }
      } else {
        #pragma unroll
        for (int nf = 0; nf < 4; ++nf)
          #pragma unroll
          for (int r = 0; r < 4; ++r)
            s[nf][r] *= sc2;
      }

      // defer-max (T13, THR=8 in log2 units): wave-uniform check
      bool need = false;
      float lm[4];
      #pragma unroll
      for (int r = 0; r < 4; ++r) {
        lm[r] = fmaxf(fmaxf(s[0][r], s[1][r]), fmaxf(s[2][r], s[3][r]));
        need = need || (lm[r] > m_r[r] + 8.f);
      }
      if (__any((int)need)) {
        #pragma unroll
        for (int r = 0; r < 4; ++r) {
          float mx = lm[r];
          #pragma unroll
          for (int mk = 1; mk < 16; mk <<= 1) mx = fmaxf(mx, __shfl_xor(mx, mk));
          float mo = m_r[r];
          float mn = fmaxf(mo, mx);
          float alpha = exp2f(mo - mn);
          m_r[r] = mn;
          l_r[r] *= alpha;
          #pragma unroll
          for (int df = 0; df < 8; ++df) oacc[df][r] *= alpha;
        }
      }

      // P = exp2(s - m), row-sum (always)
      #pragma unroll
      for (int r = 0; r < 4; ++r) {
        float rs = 0.f;
        #pragma unroll
        for (int nf = 0; nf < 4; ++nf) {
          float p = exp2f(s[nf][r] - m_r[r]);
          s[nf][r] = p;
          rs += p;
        }
        #pragma unroll
        for (int mk = 1; mk < 16; mk <<= 1) rs += __shfl_xor(rs, mk);
        l_r[r] += rs;
      }

      // P -> LDS (per-wave region), then PV (setprio around MFMA cluster)
      #pragma unroll
      for (int nf = 0; nf < 4; ++nf)
        #pragma unroll
        for (int r = 0; r < 4; ++r)
          lP[w][(lg * 4 + r) * 72 + nf * 16 + lr] = __float2bfloat16(s[nf][r]);
      asm volatile("s_waitcnt lgkmcnt(0)" ::: "memory");

      #pragma unroll
      for (int ks2 = 0; ks2 < 2; ++ks2) {
        bf16x8 pa = *(const bf16x8*)&lP[w][lr * 72 + ks2 * 32 + lg * 8];
        __builtin_amdgcn_s_setprio(1);
        #pragma unroll
        for (int df = 0; df < 8; ++df) {
          int row = df * 16 + lr;
          bf16x8 vf = *(const bf16x8*)&lV[cur][row * 64 + ((ks2 * 4 + lg) ^ (row & 7)) * 8];
          oacc[df] = __builtin_amdgcn_mfma_f32_16x16x32_bf16(pa, vf, oacc[df], 0, 0, 0);
        }
        __builtin_amdgcn_s_setprio(0);
      }
      __syncthreads();                      // drains next-tile stage (vmcnt 0) + LDS
      cur ^= 1;
    }

    // normalize + write O[s][h*128+d]
    #pragma unroll
    for (int r = 0; r < 4; ++r) {
      float inv = 1.f / l_r[r];
      long q = q0 + w * 16 + lg * 4 + r;
      #pragma unroll
      for (int df = 0; df < 8; ++df)
        O[q * HID + h * HD + df * 16 + lr] = __float2bfloat16(oacc[df][r] * inv);
    }
    __syncthreads();                        // phase boundary: lK/lV reuse
  }
}

// ---------- launcher ----------
extern "C" void kernel_launch(void* const* d_in, const int* in_sizes, int n_in,
                              void* d_out, int out_size, void* d_ws, size_t ws_size,
                              hipStream_t stream)
{
  (void)in_sizes; (void)n_in; (void)out_size;
  const float* hidden = (const float*)d_in[0];
  const int*   pos    = (const int*)d_in[1];
  const float* wqkv_w = (const float*)d_in[2];
  const float* wqkv_b = (const float*)d_in[3];
  const float* wo_w   = (const float*)d_in[4];
  const float* wo_b   = (const float*)d_in[5];
  float* out = (float*)d_out;

  // ws layout (bytes). Phase 1: hid_bf | wqkv_bf | qkv_bf.
  // Phase 2+ reuses hid_bf region as Qr, wqkv_bf region as Kr/Vt/Obf/Wo_bf/tables.
  char* ws = (char*)d_ws;
  if (ws_size < 167772160UL) return;        // need 160 MB
  __hip_bfloat16* hid_bf  = (__hip_bfloat16*)(ws + 0);          // 16 MB, later Qr
  __hip_bfloat16* wqkv_bf = (__hip_bfloat16*)(ws + 16777216);   // 96 MB
  __hip_bfloat16* qr      = (__hip_bfloat16*)(ws + 0);
  __hip_bfloat16* kr      = (__hip_bfloat16*)(ws + 16777216);
  __hip_bfloat16* vt      = (__hip_bfloat16*)(ws + 33554432);
  __hip_bfloat16* obf     = (__hip_bfloat16*)(ws + 50331648);
  __hip_bfloat16* wo_bf   = (__hip_bfloat16*)(ws + 67108864);   // 32 MB
  float*          cos_t   = (float*)(ws + 100663296);
  float*          sin_t   = (float*)(ws + 100663296 + 524288);
  __hip_bfloat16* qkv_bf  = (__hip_bfloat16*)(ws + 117440512);  // 48 MB -> total 160 MB

  cvt_bf16_kernel<<<4096, 256, 0, stream>>>(hidden, hid_bf, 8388608L);
  cvt_bf16_kernel<<<8192, 256, 0, stream>>>(wqkv_w, wqkv_bf, 50331648L);
  gemm_bt_kernel<1><<<dim3(8, 96), 256, 0, stream>>>(hid_bf, wqkv_bf, wqkv_b, qkv_bf, 2048, 12288, 4096);
  // safe to overwrite wqkv region only after the QKV GEMM
  cvt_bf16_kernel<<<8192, 256, 0, stream>>>(wo_w, wo_bf, 16777216L);
  rope_table_kernel<<<2048, 64, 0, stream>>>(pos, cos_t, sin_t);
  rope_rearrange_kernel<<<dim3(32, 32), 256, 0, stream>>>(qkv_bf, cos_t, sin_t, qr, kr, vt);
  flash_attn_kernel<<<dim3(16, 32), 256, 0, stream>>>(qr, kr, vt, obf);
  gemm_bt_kernel<0><<<dim3(8, 32), 256, 0, stream>>>(obf, wo_bf, wo_b, out, 2048, 4096, 4096);
}

// Round 18
// 523.839 us; speedup vs baseline: 1.1676x; 1.1676x over previous
//
#include <hip/hip_runtime.h>
#include <hip/hip_bf16.h>

// ---------- types ----------
typedef short bf16x8 __attribute__((ext_vector_type(8)));   // 8 bf16 (4 VGPRs)
typedef float f32x4  __attribute__((ext_vector_type(4)));
typedef float f32x16 __attribute__((ext_vector_type(16)));  // 32x32 MFMA acc

typedef __attribute__((address_space(1))) const unsigned int gu32_t;
typedef __attribute__((address_space(3))) unsigned int lu32_t;

__device__ inline void gld16(const void* g, void* l) {
  // async global->LDS, 16B per lane; dest must be wave-uniform-base + lane*16
  __builtin_amdgcn_global_load_lds((gu32_t*)g, (lu32_t*)l, 16, 0, 0);
}

__device__ inline float bf2f(__hip_bfloat16 x) { return __bfloat162float(x); }

#define S_LEN 2048
#define HID   4096
#define NH    32
#define HD    128
#define QKV_N 12288

// ---------- fp32 -> bf16 convert (vectorized, grid-stride) ----------
__global__ void cvt_bf16_kernel(const float* __restrict__ in,
                                __hip_bfloat16* __restrict__ out, long n) {
  long stride = (long)gridDim.x * blockDim.x;
  for (long i = (long)blockIdx.x * blockDim.x + threadIdx.x; i * 8 < n; i += stride) {
    long b = i * 8;
    float4 a0 = *(const float4*)(in + b);
    float4 a1 = *(const float4*)(in + b + 4);
    union { __hip_bfloat16 h[8]; bf16x8 v; } u;
    u.h[0] = __float2bfloat16(a0.x); u.h[1] = __float2bfloat16(a0.y);
    u.h[2] = __float2bfloat16(a0.z); u.h[3] = __float2bfloat16(a0.w);
    u.h[4] = __float2bfloat16(a1.x); u.h[5] = __float2bfloat16(a1.y);
    u.h[6] = __float2bfloat16(a1.z); u.h[7] = __float2bfloat16(a1.w);
    *(bf16x8*)(out + b) = u.v;
  }
}

// ---------- GEMM (R16 geometry: 128x128 block, 32x32x16 MFMA, REVERTED) ------
// R17's 256x128 retile regressed (1 block/CU resident, exposed latency) —
// lesson: this 2-barrier structure needs >=2 blocks/CU; reverted to R16.
// ROUND 18: B operand is now FP32 (the raw weight matrix) — the fp32->bf16
// weight convert is FUSED into B staging via reg-staging: 2x float4 loads,
// in-register __float2bfloat16 (same RTN rounding as the old cvt kernel ->
// LDS contents bitwise identical), ds_write_b128 to the WRITE-side-swizzled
// slot (s ^ (row&7)); fragment reads unchanged. Per-8-lane group: same row,
// distinct slots -> all 32 banks (write conflict-free); global fp32 reads
// 256B-contiguous per 8 lanes. A staging (gld16, source-preswizzled) and
// the entire MFMA loop are byte-identical to R16.
// Eliminates the wqkv_w (48us) and wo_w (16us) convert dispatches.
// T1 XCD chunk swizzle unchanged. GEMMs are compute-bound (HBM 13%,
// VALU 12%) so the extra fp32 B traffic + cvt VALU fits in headroom.
template<int WRITE_BF16>
__global__ __launch_bounds__(256) void gemm_bt_kernel(
    const __hip_bfloat16* __restrict__ A,
    const float* __restrict__ Bf,
    const float* __restrict__ bias,
    void* __restrict__ Cout, int M, int N, int K)
{
  __shared__ __hip_bfloat16 lA[128 * 64];
  __shared__ __hip_bfloat16 lB[128 * 64];
  const int t = threadIdx.x;
  const int w = t >> 6, l = t & 63;
  const int l31 = l & 31, lh = l >> 5;
  const int nwg = gridDim.x * gridDim.y;
  const int bid = blockIdx.y * gridDim.x + blockIdx.x;
  const int swz = (bid & 7) * (nwg >> 3) + (bid >> 3);   // XCD chunk swizzle
  const int m0 = (swz % gridDim.x) * 128, n0 = (swz / gridDim.x) * 128;
  const int wm = (w >> 1) * 64, wn = (w & 1) * 64;

  f32x16 acc[2][2] = {};

  for (int k0 = 0; k0 < K; k0 += 64) {
    #pragma unroll
    for (int i = 0; i < 4; ++i) {           // A tile: async gld16 (bf16 input)
      int c = i * 256 + t;
      int row = c >> 3, s = c & 7;          // source slot pre-swizzled
      gld16(A + (long)(m0 + row) * K + k0 + (s ^ (row & 7)) * 8, &lA[c * 8]);
    }
    #pragma unroll
    for (int i = 0; i < 4; ++i) {           // B tile: fp32 reg-stage + convert
      int c = i * 256 + t;
      int row = c >> 3, s = c & 7;
      const float* bp = Bf + (long)(n0 + row) * K + k0 + s * 8;
      float4 f0 = *(const float4*)(bp);
      float4 f1 = *(const float4*)(bp + 4);
      union { __hip_bfloat16 h[8]; bf16x8 v; } u;
      u.h[0] = __float2bfloat16(f0.x); u.h[1] = __float2bfloat16(f0.y);
      u.h[2] = __float2bfloat16(f0.z); u.h[3] = __float2bfloat16(f0.w);
      u.h[4] = __float2bfloat16(f1.x); u.h[5] = __float2bfloat16(f1.y);
      u.h[6] = __float2bfloat16(f1.z); u.h[7] = __float2bfloat16(f1.w);
      *(bf16x8*)&lB[row * 64 + (s ^ (row & 7)) * 8] = u.v;   // write-side swizzle
    }
    __syncthreads();                        // drains vmcnt+lgkmcnt before barrier
    #pragma unroll
    for (int kk = 0; kk < 4; ++kk) {        // K=16 per MFMA, 4 per K-step
      bf16x8 af[2], bfr[2];
      #pragma unroll
      for (int mt = 0; mt < 2; ++mt) {
        int row = wm + mt * 32 + l31;
        int slot = (kk * 2 + lh) ^ (row & 7);
        af[mt] = *(const bf16x8*)&lA[row * 64 + slot * 8];
      }
      #pragma unroll
      for (int nt = 0; nt < 2; ++nt) {
        int row = wn + nt * 32 + l31;
        int slot = (kk * 2 + lh) ^ (row & 7);
        bfr[nt] = *(const bf16x8*)&lB[row * 64 + slot * 8];
      }
      #pragma unroll
      for (int mt = 0; mt < 2; ++mt)
        #pragma unroll
        for (int nt = 0; nt < 2; ++nt)
          acc[mt][nt] = __builtin_amdgcn_mfma_f32_32x32x16_bf16(af[mt], bfr[nt], acc[mt][nt], 0, 0, 0);
    }
    __syncthreads();
  }

  #pragma unroll
  for (int mt = 0; mt < 2; ++mt) {
    #pragma unroll
    for (int nt = 0; nt < 2; ++nt) {
      int col = n0 + wn + nt * 32 + l31;
      float bv = bias[col];
      #pragma unroll
      for (int reg = 0; reg < 16; ++reg) {
        // C/D 32x32: col=lane&31, row=(reg&3)+8*(reg>>2)+4*(lane>>5)
        int row = m0 + wm + mt * 32 + (reg & 3) + 8 * (reg >> 2) + 4 * lh;
        float v = acc[mt][nt][reg] + bv;
        if (WRITE_BF16)
          ((__hip_bfloat16*)Cout)[(long)row * N + col] = __float2bfloat16(v);
        else
          ((float*)Cout)[(long)row * N + col] = v;
      }
    }
  }
}

// ---------- RoPE cos/sin table: [s][64] ----------
__global__ void rope_table_kernel(const int* __restrict__ pos,
                                  float* __restrict__ ct, float* __restrict__ st) {
  int s = blockIdx.x, j = threadIdx.x;      // 2048 x 64
  float p = (float)pos[s];
  float invf = exp2f(-0.20762050593046013f * (float)j);
  float a = p * invf;
  ct[s * 64 + j] = cosf(a);
  st[s * 64 + j] = sinf(a);
}

// ---------- RoPE + rearrange (vectorized, R13) ----------
__global__ __launch_bounds__(256) void rope_rearrange_kernel(
    const __hip_bfloat16* __restrict__ qkv,
    const float* __restrict__ ct, const float* __restrict__ st,
    __hip_bfloat16* __restrict__ Qr, __hip_bfloat16* __restrict__ Kr,
    __hip_bfloat16* __restrict__ Vt)
{
  __shared__ __hip_bfloat16 lv[64][136];    // padded to break bank conflicts on transpose read
  const int h = blockIdx.y, s0 = blockIdx.x * 64, t = threadIdx.x;

  #pragma unroll
  for (int half = 0; half < 2; ++half) {
    int si = half * 32 + (t >> 3);          // row within tile
    int jo = (t & 7) * 8;                   // 8 consecutive j per lane
    long base = (long)(s0 + si) * QKV_N + h * 384;
    union { __hip_bfloat16 h8[8]; bf16x8 v; } q1, q2, k1, k2, o;
    q1.v = *(const bf16x8*)(qkv + base + jo);
    q2.v = *(const bf16x8*)(qkv + base + 64 + jo);
    k1.v = *(const bf16x8*)(qkv + base + 128 + jo);
    k2.v = *(const bf16x8*)(qkv + base + 192 + jo);
    const float* cp = ct + (s0 + si) * 64 + jo;
    const float* sp = st + (s0 + si) * 64 + jo;
    long ob = (long)h * (S_LEN * HD) + (long)(s0 + si) * HD;
    #pragma unroll
    for (int e = 0; e < 8; ++e)
      o.h8[e] = __float2bfloat16(bf2f(q1.h8[e]) * cp[e] - bf2f(q2.h8[e]) * sp[e]);
    *(bf16x8*)(Qr + ob + jo) = o.v;
    #pragma unroll
    for (int e = 0; e < 8; ++e)
      o.h8[e] = __float2bfloat16(bf2f(q2.h8[e]) * cp[e] + bf2f(q1.h8[e]) * sp[e]);
    *(bf16x8*)(Qr + ob + 64 + jo) = o.v;
    #pragma unroll
    for (int e = 0; e < 8; ++e)
      o.h8[e] = __float2bfloat16(bf2f(k1.h8[e]) * cp[e] - bf2f(k2.h8[e]) * sp[e]);
    *(bf16x8*)(Kr + ob + jo) = o.v;
    #pragma unroll
    for (int e = 0; e < 8; ++e)
      o.h8[e] = __float2bfloat16(bf2f(k2.h8[e]) * cp[e] + bf2f(k1.h8[e]) * sp[e]);
    *(bf16x8*)(Kr + ob + 64 + jo) = o.v;
    *(bf16x8*)&lv[si][jo]      = *(const bf16x8*)(qkv + base + 256 + jo);
    *(bf16x8*)&lv[si][64 + jo] = *(const bf16x8*)(qkv + base + 320 + jo);
  }
  __syncthreads();
  #pragma unroll
  for (int i = 0; i < 4; ++i) {
    int c = i * 256 + t;                    // 128 d x 8 chunks of 8 s
    int d = c >> 3, s8 = (c & 7) * 8;
    union { __hip_bfloat16 h8[8]; bf16x8 v; } u;
    #pragma unroll
    for (int j2 = 0; j2 < 8; ++j2) u.h8[j2] = lv[s8 + j2][d];
    *(bf16x8*)(Vt + (long)h * (HD * S_LEN) + (long)d * S_LEN + s0 + s8) = u.v;
  }
}

// ---------- causal flash attention (R15 config: frozen) ----------
// QBLK=64, paired q-tiles {p, 31-p} -> 33 k-tiles/block uniform, grid 16x32.
// K/V dbuf; log2 softmax, diagonal-only mask, T13 defer-max; T5 setprio.
// lK: 16 slots/row swizzle row&15; lV: 8 slots/row swizzle row&7 (T2).
#define FA_STAGE(buf, k0_) do {                                              \
    _Pragma("unroll")                                                        \
    for (int i_ = 0; i_ < 4; ++i_) {       /* K tile: 64 k x 128 d */        \
      int c_ = i_ * 256 + t;                                                 \
      int row_ = c_ >> 4, s_ = c_ & 15;                                      \
      gld16(Kh + (long)((k0_) + row_) * HD + (s_ ^ (row_ & 15)) * 8,         \
            &lK[buf][c_ * 8]);                                               \
    }                                                                        \
    _Pragma("unroll")                                                        \
    for (int i_ = 0; i_ < 4; ++i_) {       /* V^T tile: 128 d x 64 k */      \
      int c_ = i_ * 256 + t;                                                 \
      int d_ = c_ >> 3, s_ = c_ & 7;                                         \
      gld16(Vh + (long)d_ * S_LEN + (k0_) + (s_ ^ (d_ & 7)) * 8,             \
            &lV[buf][c_ * 8]);                                               \
    } } while (0)

__global__ __launch_bounds__(256) void flash_attn_kernel(
    const __hip_bfloat16* __restrict__ Qr, const __hip_bfloat16* __restrict__ Kr,
    const __hip_bfloat16* __restrict__ Vt, __hip_bfloat16* __restrict__ O)
{
  __shared__ __hip_bfloat16 lK[2][64 * 128];   // 2 x 16KB
  __shared__ __hip_bfloat16 lV[2][128 * 64];   // 2 x 16KB
  __shared__ __hip_bfloat16 lP[4][16 * 72];    // per-wave P, padded stride
  const int h = blockIdx.y, pair = blockIdx.x;
  const int t = threadIdx.x, w = t >> 6, l = t & 63;
  const int lr = l & 15, lg = l >> 4;
  const __hip_bfloat16* Qh = Qr + (long)h * (S_LEN * HD);
  const __hip_bfloat16* Kh = Kr + (long)h * (S_LEN * HD);
  const __hip_bfloat16* Vh = Vt + (long)h * (HD * S_LEN);
  const float sc2 = 0.12751744f;            // (1/sqrt(128)) * log2(e)

  for (int ph = 0; ph < 2; ++ph) {
    const int qt = ph ? (31 - pair) : pair;
    const int q0 = qt * 64;

    // hoist this q-tile's Q fragments to registers
    bf16x8 qf[4];
    #pragma unroll
    for (int ks = 0; ks < 4; ++ks)
      qf[ks] = *(const bf16x8*)(Qh + (long)(q0 + w * 16 + lr) * HD + ks * 32 + lg * 8);

    float m_r[4], l_r[4];
    f32x4 oacc[8] = {};
    #pragma unroll
    for (int r = 0; r < 4; ++r) { m_r[r] = -1e30f; l_r[r] = 0.f; }

    const int ktiles = qt + 1;              // causal: k <= q0+63
    int cur = 0;
    FA_STAGE(0, 0);                         // prologue: tile 0 -> buf0
    __syncthreads();                        // drains vmcnt(0)

    for (int kt = 0; kt < ktiles; ++kt) {
      const int k0 = kt * 64;
      if (kt + 1 < ktiles) FA_STAGE(cur ^ 1, k0 + 64);   // overlap with compute

      // S = Q K^T (one 16-row m-frag per wave), setprio around MFMA cluster
      f32x4 s[4] = {};
      #pragma unroll
      for (int ks = 0; ks < 4; ++ks) {
        bf16x8 kf[4];
        #pragma unroll
        for (int nf = 0; nf < 4; ++nf) {
          int row = nf * 16 + lr;
          kf[nf] = *(const bf16x8*)&lK[cur][row * 128 + ((ks * 4 + lg) ^ (row & 15)) * 8];
        }
        __builtin_amdgcn_s_setprio(1);
        #pragma unroll
        for (int nf = 0; nf < 4; ++nf)
          s[nf] = __builtin_amdgcn_mfma_f32_16x16x32_bf16(qf[ks], kf[nf], s[nf], 0, 0, 0);
        __builtin_amdgcn_s_setprio(0);
      }

      // scale to log2 domain; causal mask only on the diagonal tile
      if (kt == qt) {
        #pragma unroll
        for (int nf = 0; nf < 4; ++nf) {
          int k = k0 + nf * 16 + lr;
          #pragma unroll
          for (int r = 0; r < 4; ++r) {
            int q = q0 + w * 16 + lg * 4 + r;
            float v = s[nf][r] * sc2;
            s[nf][r] = (k > q) ? -1e30f : v;
          }
        }
      } else {
        #pragma unroll
        for (int nf = 0; nf < 4; ++nf)
          #pragma unroll
          for (int r = 0; r < 4; ++r)
            s[nf][r] *= sc2;
      }

      // defer-max (T13, THR=8 in log2 units): wave-uniform check
      bool need = false;
      float lm[4];
      #pragma unroll
      for (int r = 0; r < 4; ++r) {
        lm[r] = fmaxf(fmaxf(s[0][r], s[1][r]), fmaxf(s[2][r], s[3][r]));
        need = need || (lm[r] > m_r[r] + 8.f);
      }
      if (__any((int)need)) {
        #pragma unroll
        for (int r = 0; r < 4; ++r) {
          float mx = lm[r];
          #pragma unroll
          for (int mk = 1; mk < 16; mk <<= 1) mx = fmaxf(mx, __shfl_xor(mx, mk));
          float mo = m_r[r];
          float mn = fmaxf(mo, mx);
          float alpha = exp2f(mo - mn);
          m_r[r] = mn;
          l_r[r] *= alpha;
          #pragma unroll
          for (int df = 0; df < 8; ++df) oacc[df][r] *= alpha;
        }
      }

      // P = exp2(s - m), row-sum (always)
      #pragma unroll
      for (int r = 0; r < 4; ++r) {
        float rs = 0.f;
        #pragma unroll
        for (int nf = 0; nf < 4; ++nf) {
          float p = exp2f(s[nf][r] - m_r[r]);
          s[nf][r] = p;
          rs += p;
        }
        #pragma unroll
        for (int mk = 1; mk < 16; mk <<= 1) rs += __shfl_xor(rs, mk);
        l_r[r] += rs;
      }

      // P -> LDS (per-wave region), then PV (setprio around MFMA cluster)
      #pragma unroll
      for (int nf = 0; nf < 4; ++nf)
        #pragma unroll
        for (int r = 0; r < 4; ++r)
          lP[w][(lg * 4 + r) * 72 + nf * 16 + lr] = __float2bfloat16(s[nf][r]);
      asm volatile("s_waitcnt lgkmcnt(0)" ::: "memory");

      #pragma unroll
      for (int ks2 = 0; ks2 < 2; ++ks2) {
        bf16x8 pa = *(const bf16x8*)&lP[w][lr * 72 + ks2 * 32 + lg * 8];
        __builtin_amdgcn_s_setprio(1);
        #pragma unroll
        for (int df = 0; df < 8; ++df) {
          int row = df * 16 + lr;
          bf16x8 vf = *(const bf16x8*)&lV[cur][row * 64 + ((ks2 * 4 + lg) ^ (row & 7)) * 8];
          oacc[df] = __builtin_amdgcn_mfma_f32_16x16x32_bf16(pa, vf, oacc[df], 0, 0, 0);
        }
        __builtin_amdgcn_s_setprio(0);
      }
      __syncthreads();                      // drains next-tile stage (vmcnt 0) + LDS
      cur ^= 1;
    }

    // normalize + write O[s][h*128+d]
    #pragma unroll
    for (int r = 0; r < 4; ++r) {
      float inv = 1.f / l_r[r];
      long q = q0 + w * 16 + lg * 4 + r;
      #pragma unroll
      for (int df = 0; df < 8; ++df)
        O[q * HID + h * HD + df * 16 + lr] = __float2bfloat16(oacc[df][r] * inv);
    }
    __syncthreads();                        // phase boundary: lK/lV reuse
  }
}

// ---------- launcher ----------
extern "C" void kernel_launch(void* const* d_in, const int* in_sizes, int n_in,
                              void* d_out, int out_size, void* d_ws, size_t ws_size,
                              hipStream_t stream)
{
  (void)in_sizes; (void)n_in; (void)out_size;
  const float* hidden = (const float*)d_in[0];
  const int*   pos    = (const int*)d_in[1];
  const float* wqkv_w = (const float*)d_in[2];
  const float* wqkv_b = (const float*)d_in[3];
  const float* wo_w   = (const float*)d_in[4];
  const float* wo_b   = (const float*)d_in[5];
  float* out = (float*)d_out;

  // ws layout (bytes). R18: weight bf16 buffers no longer needed (convert
  // fused into GEMM B-staging); only hidden is pre-converted.
  char* ws = (char*)d_ws;
  if (ws_size < 167772160UL) return;        // need 160 MB
  __hip_bfloat16* hid_bf  = (__hip_bfloat16*)(ws + 0);          // 16 MB, later Qr
  __hip_bfloat16* qr      = (__hip_bfloat16*)(ws + 0);
  __hip_bfloat16* kr      = (__hip_bfloat16*)(ws + 16777216);
  __hip_bfloat16* vt      = (__hip_bfloat16*)(ws + 33554432);
  __hip_bfloat16* obf     = (__hip_bfloat16*)(ws + 50331648);
  float*          cos_t   = (float*)(ws + 100663296);
  float*          sin_t   = (float*)(ws + 100663296 + 524288);
  __hip_bfloat16* qkv_bf  = (__hip_bfloat16*)(ws + 117440512);  // 48 MB

  cvt_bf16_kernel<<<4096, 256, 0, stream>>>(hidden, hid_bf, 8388608L);
  gemm_bt_kernel<1><<<dim3(16, 96), 256, 0, stream>>>(hid_bf, wqkv_w, wqkv_b, qkv_bf, 2048, 12288, 4096);
  rope_table_kernel<<<2048, 64, 0, stream>>>(pos, cos_t, sin_t);
  rope_rearrange_kernel<<<dim3(32, 32), 256, 0, stream>>>(qkv_bf, cos_t, sin_t, qr, kr, vt);
  flash_attn_kernel<<<dim3(16, 32), 256, 0, stream>>>(qr, kr, vt, obf);
  gemm_bt_kernel<0><<<dim3(16, 32), 256, 0, stream>>>(obf, wo_w, wo_b, out, 2048, 4096, 4096);
}

// Round 19
// 467.752 us; speedup vs baseline: 1.3076x; 1.1199x over previous
//
#include <hip/hip_runtime.h>
#include <hip/hip_bf16.h>

// ---------- types ----------
typedef short bf16x8 __attribute__((ext_vector_type(8)));   // 8 bf16 (4 VGPRs)
typedef float f32x4  __attribute__((ext_vector_type(4)));
typedef float f32x16 __attribute__((ext_vector_type(16)));  // 32x32 MFMA acc

typedef __attribute__((address_space(1))) const unsigned int gu32_t;
typedef __attribute__((address_space(3))) unsigned int lu32_t;

__device__ inline void gld16(const void* g, void* l) {
  // async global->LDS, 16B per lane; dest must be wave-uniform-base + lane*16
  __builtin_amdgcn_global_load_lds((gu32_t*)g, (lu32_t*)l, 16, 0, 0);
}

__device__ inline float bf2f(__hip_bfloat16 x) { return __bfloat162float(x); }

#define S_LEN 2048
#define HID   4096
#define NH    32
#define HD    128
#define QKV_N 12288

// ---------- fp32 -> bf16 convert (vectorized, grid-stride) ----------
// R19: separate converts RESTORED (R18's fused-into-GEMM variant doubled B's
// HBM/L2 footprint and serialized staging; QKV 236->339us. Reverted.)
__global__ void cvt_bf16_kernel(const float* __restrict__ in,
                                __hip_bfloat16* __restrict__ out, long n) {
  long stride = (long)gridDim.x * blockDim.x;
  for (long i = (long)blockIdx.x * blockDim.x + threadIdx.x; i * 8 < n; i += stride) {
    long b = i * 8;
    float4 a0 = *(const float4*)(in + b);
    float4 a1 = *(const float4*)(in + b + 4);
    union { __hip_bfloat16 h[8]; bf16x8 v; } u;
    u.h[0] = __float2bfloat16(a0.x); u.h[1] = __float2bfloat16(a0.y);
    u.h[2] = __float2bfloat16(a0.z); u.h[3] = __float2bfloat16(a0.w);
    u.h[4] = __float2bfloat16(a1.x); u.h[5] = __float2bfloat16(a1.y);
    u.h[6] = __float2bfloat16(a1.z); u.h[7] = __float2bfloat16(a1.w);
    *(bf16x8*)(out + b) = u.v;
  }
}

// ---------- GEMM (R16 geometry + widened XOR key): C = A B^T + bias ----------
// 128x128 block, 4 waves (2x2), 32x32x16 MFMA (VALUBusy 49->12 vs 16x16).
// ROUND 19 fix: R16's 32x32 fragment reads (row = lane&31) had 2.5e7
// bank-conflict cycles. Rows are 128B = exactly 32 banks, so bank depends
// only on slot; slot = g ^ (row&7) collides 4-way among lanes whose rows
// differ by 8. Widened key f(row) = (row&7) ^ ((row>>3)&3): rows r and r+8
// now map to different slots -> max 2 lanes/bank per 16-lane phase (free,
// m136). Both-sides rule: same f on gld16 SOURCE slot and fragment-read
// slot; per-row bijection (XOR const), staging coalescing unchanged
// (permutation stays within each 128B row).
// T1 XCD chunk swizzle unchanged.
#define SWZ(row) (((row) & 7) ^ (((row) >> 3) & 3))
template<int WRITE_BF16>
__global__ __launch_bounds__(256) void gemm_bt_kernel(
    const __hip_bfloat16* __restrict__ A,
    const __hip_bfloat16* __restrict__ B,
    const float* __restrict__ bias,
    void* __restrict__ Cout, int M, int N, int K)
{
  __shared__ __hip_bfloat16 lA[128 * 64];
  __shared__ __hip_bfloat16 lB[128 * 64];
  const int t = threadIdx.x;
  const int w = t >> 6, l = t & 63;
  const int l31 = l & 31, lh = l >> 5;
  const int nwg = gridDim.x * gridDim.y;
  const int bid = blockIdx.y * gridDim.x + blockIdx.x;
  const int swz = (bid & 7) * (nwg >> 3) + (bid >> 3);   // XCD chunk swizzle
  const int m0 = (swz % gridDim.x) * 128, n0 = (swz / gridDim.x) * 128;
  const int wm = (w >> 1) * 64, wn = (w & 1) * 64;

  f32x16 acc[2][2] = {};

  for (int k0 = 0; k0 < K; k0 += 64) {
    #pragma unroll
    for (int i = 0; i < 4; ++i) {
      int c = i * 256 + t;            // chunk id 0..1023, 16B each, linear in LDS
      int row = c >> 3, s = c & 7;    // source slot pre-swizzled: s ^ f(row)
      gld16(A + (long)(m0 + row) * K + k0 + (s ^ SWZ(row)) * 8, &lA[c * 8]);
    }
    #pragma unroll
    for (int i = 0; i < 4; ++i) {
      int c = i * 256 + t;
      int row = c >> 3, s = c & 7;
      gld16(B + (long)(n0 + row) * K + k0 + (s ^ SWZ(row)) * 8, &lB[c * 8]);
    }
    __syncthreads();                  // drains vmcnt before barrier
    #pragma unroll
    for (int kk = 0; kk < 4; ++kk) {  // K=16 per MFMA, 4 per K-step
      bf16x8 af[2], bfr[2];
      #pragma unroll
      for (int mt = 0; mt < 2; ++mt) {
        int row = wm + mt * 32 + l31;
        int slot = (kk * 2 + lh) ^ SWZ(row);
        af[mt] = *(const bf16x8*)&lA[row * 64 + slot * 8];
      }
      #pragma unroll
      for (int nt = 0; nt < 2; ++nt) {
        int row = wn + nt * 32 + l31;
        int slot = (kk * 2 + lh) ^ SWZ(row);
        bfr[nt] = *(const bf16x8*)&lB[row * 64 + slot * 8];
      }
      #pragma unroll
      for (int mt = 0; mt < 2; ++mt)
        #pragma unroll
        for (int nt = 0; nt < 2; ++nt)
          acc[mt][nt] = __builtin_amdgcn_mfma_f32_32x32x16_bf16(af[mt], bfr[nt], acc[mt][nt], 0, 0, 0);
    }
    __syncthreads();
  }

  #pragma unroll
  for (int mt = 0; mt < 2; ++mt) {
    #pragma unroll
    for (int nt = 0; nt < 2; ++nt) {
      int col = n0 + wn + nt * 32 + l31;
      float bv = bias[col];
      #pragma unroll
      for (int reg = 0; reg < 16; ++reg) {
        // C/D 32x32: col=lane&31, row=(reg&3)+8*(reg>>2)+4*(lane>>5)
        int row = m0 + wm + mt * 32 + (reg & 3) + 8 * (reg >> 2) + 4 * lh;
        float v = acc[mt][nt][reg] + bv;
        if (WRITE_BF16)
          ((__hip_bfloat16*)Cout)[(long)row * N + col] = __float2bfloat16(v);
        else
          ((float*)Cout)[(long)row * N + col] = v;
      }
    }
  }
}

// ---------- RoPE cos/sin table: [s][64] ----------
__global__ void rope_table_kernel(const int* __restrict__ pos,
                                  float* __restrict__ ct, float* __restrict__ st) {
  int s = blockIdx.x, j = threadIdx.x;      // 2048 x 64
  float p = (float)pos[s];
  float invf = exp2f(-0.20762050593046013f * (float)j);
  float a = p * invf;
  ct[s * 64 + j] = cosf(a);
  st[s * 64 + j] = sinf(a);
}

// ---------- RoPE + rearrange (vectorized, R13) ----------
__global__ __launch_bounds__(256) void rope_rearrange_kernel(
    const __hip_bfloat16* __restrict__ qkv,
    const float* __restrict__ ct, const float* __restrict__ st,
    __hip_bfloat16* __restrict__ Qr, __hip_bfloat16* __restrict__ Kr,
    __hip_bfloat16* __restrict__ Vt)
{
  __shared__ __hip_bfloat16 lv[64][136];    // padded to break bank conflicts on transpose read
  const int h = blockIdx.y, s0 = blockIdx.x * 64, t = threadIdx.x;

  #pragma unroll
  for (int half = 0; half < 2; ++half) {
    int si = half * 32 + (t >> 3);          // row within tile
    int jo = (t & 7) * 8;                   // 8 consecutive j per lane
    long base = (long)(s0 + si) * QKV_N + h * 384;
    union { __hip_bfloat16 h8[8]; bf16x8 v; } q1, q2, k1, k2, o;
    q1.v = *(const bf16x8*)(qkv + base + jo);
    q2.v = *(const bf16x8*)(qkv + base + 64 + jo);
    k1.v = *(const bf16x8*)(qkv + base + 128 + jo);
    k2.v = *(const bf16x8*)(qkv + base + 192 + jo);
    const float* cp = ct + (s0 + si) * 64 + jo;
    const float* sp = st + (s0 + si) * 64 + jo;
    long ob = (long)h * (S_LEN * HD) + (long)(s0 + si) * HD;
    #pragma unroll
    for (int e = 0; e < 8; ++e)
      o.h8[e] = __float2bfloat16(bf2f(q1.h8[e]) * cp[e] - bf2f(q2.h8[e]) * sp[e]);
    *(bf16x8*)(Qr + ob + jo) = o.v;
    #pragma unroll
    for (int e = 0; e < 8; ++e)
      o.h8[e] = __float2bfloat16(bf2f(q2.h8[e]) * cp[e] + bf2f(q1.h8[e]) * sp[e]);
    *(bf16x8*)(Qr + ob + 64 + jo) = o.v;
    #pragma unroll
    for (int e = 0; e < 8; ++e)
      o.h8[e] = __float2bfloat16(bf2f(k1.h8[e]) * cp[e] - bf2f(k2.h8[e]) * sp[e]);
    *(bf16x8*)(Kr + ob + jo) = o.v;
    #pragma unroll
    for (int e = 0; e < 8; ++e)
      o.h8[e] = __float2bfloat16(bf2f(k2.h8[e]) * cp[e] + bf2f(k1.h8[e]) * sp[e]);
    *(bf16x8*)(Kr + ob + 64 + jo) = o.v;
    *(bf16x8*)&lv[si][jo]      = *(const bf16x8*)(qkv + base + 256 + jo);
    *(bf16x8*)&lv[si][64 + jo] = *(const bf16x8*)(qkv + base + 320 + jo);
  }
  __syncthreads();
  #pragma unroll
  for (int i = 0; i < 4; ++i) {
    int c = i * 256 + t;                    // 128 d x 8 chunks of 8 s
    int d = c >> 3, s8 = (c & 7) * 8;
    union { __hip_bfloat16 h8[8]; bf16x8 v; } u;
    #pragma unroll
    for (int j2 = 0; j2 < 8; ++j2) u.h8[j2] = lv[s8 + j2][d];
    *(bf16x8*)(Vt + (long)h * (HD * S_LEN) + (long)d * S_LEN + s0 + s8) = u.v;
  }
}

// ---------- causal flash attention (R15 config: frozen) ----------
// QBLK=64, paired q-tiles {p, 31-p} -> 33 k-tiles/block uniform, grid 16x32.
// K/V dbuf; log2 softmax, diagonal-only mask, T13 defer-max; T5 setprio.
// lK: 16 slots/row swizzle row&15; lV: 8 slots/row swizzle row&7 (T2).
#define FA_STAGE(buf, k0_) do {                                              \
    _Pragma("unroll")                                                        \
    for (int i_ = 0; i_ < 4; ++i_) {       /* K tile: 64 k x 128 d */        \
      int c_ = i_ * 256 + t;                                                 \
      int row_ = c_ >> 4, s_ = c_ & 15;                                      \
      gld16(Kh + (long)((k0_) + row_) * HD + (s_ ^ (row_ & 15)) * 8,         \
            &lK[buf][c_ * 8]);                                               \
    }                                                                        \
    _Pragma("unroll")                                                        \
    for (int i_ = 0; i_ < 4; ++i_) {       /* V^T tile: 128 d x 64 k */      \
      int c_ = i_ * 256 + t;                                                 \
      int d_ = c_ >> 3, s_ = c_ & 7;                                         \
      gld16(Vh + (long)d_ * S_LEN + (k0_) + (s_ ^ (d_ & 7)) * 8,             \
            &lV[buf][c_ * 8]);                                               \
    } } while (0)

__global__ __launch_bounds__(256) void flash_attn_kernel(
    const __hip_bfloat16* __restrict__ Qr, const __hip_bfloat16* __restrict__ Kr,
    const __hip_bfloat16* __restrict__ Vt, __hip_bfloat16* __restrict__ O)
{
  __shared__ __hip_bfloat16 lK[2][64 * 128];   // 2 x 16KB
  __shared__ __hip_bfloat16 lV[2][128 * 64];   // 2 x 16KB
  __shared__ __hip_bfloat16 lP[4][16 * 72];    // per-wave P, padded stride
  const int h = blockIdx.y, pair = blockIdx.x;
  const int t = threadIdx.x, w = t >> 6, l = t & 63;
  const int lr = l & 15, lg = l >> 4;
  const __hip_bfloat16* Qh = Qr + (long)h * (S_LEN * HD);
  const __hip_bfloat16* Kh = Kr + (long)h * (S_LEN * HD);
  const __hip_bfloat16* Vh = Vt + (long)h * (HD * S_LEN);
  const float sc2 = 0.12751744f;            // (1/sqrt(128)) * log2(e)

  for (int ph = 0; ph < 2; ++ph) {
    const int qt = ph ? (31 - pair) : pair;
    const int q0 = qt * 64;

    // hoist this q-tile's Q fragments to registers
    bf16x8 qf[4];
    #pragma unroll
    for (int ks = 0; ks < 4; ++ks)
      qf[ks] = *(const bf16x8*)(Qh + (long)(q0 + w * 16 + lr) * HD + ks * 32 + lg * 8);

    float m_r[4], l_r[4];
    f32x4 oacc[8] = {};
    #pragma unroll
    for (int r = 0; r < 4; ++r) { m_r[r] = -1e30f; l_r[r] = 0.f; }

    const int ktiles = qt + 1;              // causal: k <= q0+63
    int cur = 0;
    FA_STAGE(0, 0);                         // prologue: tile 0 -> buf0
    __syncthreads();                        // drains vmcnt(0)

    for (int kt = 0; kt < ktiles; ++kt) {
      const int k0 = kt * 64;
      if (kt + 1 < ktiles) FA_STAGE(cur ^ 1, k0 + 64);   // overlap with compute

      // S = Q K^T (one 16-row m-frag per wave), setprio around MFMA cluster
      f32x4 s[4] = {};
      #pragma unroll
      for (int ks = 0; ks < 4; ++ks) {
        bf16x8 kf[4];
        #pragma unroll
        for (int nf = 0; nf < 4; ++nf) {
          int row = nf * 16 + lr;
          kf[nf] = *(const bf16x8*)&lK[cur][row * 128 + ((ks * 4 + lg) ^ (row & 15)) * 8];
        }
        __builtin_amdgcn_s_setprio(1);
        #pragma unroll
        for (int nf = 0; nf < 4; ++nf)
          s[nf] = __builtin_amdgcn_mfma_f32_16x16x32_bf16(qf[ks], kf[nf], s[nf], 0, 0, 0);
        __builtin_amdgcn_s_setprio(0);
      }

      // scale to log2 domain; causal mask only on the diagonal tile
      if (kt == qt) {
        #pragma unroll
        for (int nf = 0; nf < 4; ++nf) {
          int k = k0 + nf * 16 + lr;
          #pragma unroll
          for (int r = 0; r < 4; ++r) {
            int q = q0 + w * 16 + lg * 4 + r;
            float v = s[nf][r] * sc2;
            s[nf][r] = (k > q) ? -1e30f : v;
          }
        }
      } else {
        #pragma unroll
        for (int nf = 0; nf < 4; ++nf)
          #pragma unroll
          for (int r = 0; r < 4; ++r)
            s[nf][r] *= sc2;
      }

      // defer-max (T13, THR=8 in log2 units): wave-uniform check
      bool need = false;
      float lm[4];
      #pragma unroll
      for (int r = 0; r < 4; ++r) {
        lm[r] = fmaxf(fmaxf(s[0][r], s[1][r]), fmaxf(s[2][r], s[3][r]));
        need = need || (lm[r] > m_r[r] + 8.f);
      }
      if (__any((int)need)) {
        #pragma unroll
        for (int r = 0; r < 4; ++r) {
          float mx = lm[r];
          #pragma unroll
          for (int mk = 1; mk < 16; mk <<= 1) mx = fmaxf(mx, __shfl_xor(mx, mk));
          float mo = m_r[r];
          float mn = fmaxf(mo, mx);
          float alpha = exp2f(mo - mn);
          m_r[r] = mn;
          l_r[r] *= alpha;
          #pragma unroll
          for (int df = 0; df < 8; ++df) oacc[df][r] *= alpha;
        }
      }

      // P = exp2(s - m), row-sum (always)
      #pragma unroll
      for (int r = 0; r < 4; ++r) {
        float rs = 0.f;
        #pragma unroll
        for (int nf = 0; nf < 4; ++nf) {
          float p = exp2f(s[nf][r] - m_r[r]);
          s[nf][r] = p;
          rs += p;
        }
        #pragma unroll
        for (int mk = 1; mk < 16; mk <<= 1) rs += __shfl_xor(rs, mk);
        l_r[r] += rs;
      }

      // P -> LDS (per-wave region), then PV (setprio around MFMA cluster)
      #pragma unroll
      for (int nf = 0; nf < 4; ++nf)
        #pragma unroll
        for (int r = 0; r < 4; ++r)
          lP[w][(lg * 4 + r) * 72 + nf * 16 + lr] = __float2bfloat16(s[nf][r]);
      asm volatile("s_waitcnt lgkmcnt(0)" ::: "memory");

      #pragma unroll
      for (int ks2 = 0; ks2 < 2; ++ks2) {
        bf16x8 pa = *(const bf16x8*)&lP[w][lr * 72 + ks2 * 32 + lg * 8];
        __builtin_amdgcn_s_setprio(1);
        #pragma unroll
        for (int df = 0; df < 8; ++df) {
          int row = df * 16 + lr;
          bf16x8 vf = *(const bf16x8*)&lV[cur][row * 64 + ((ks2 * 4 + lg) ^ (row & 7)) * 8];
          oacc[df] = __builtin_amdgcn_mfma_f32_16x16x32_bf16(pa, vf, oacc[df], 0, 0, 0);
        }
        __builtin_amdgcn_s_setprio(0);
      }
      __syncthreads();                      // drains next-tile stage (vmcnt 0) + LDS
      cur ^= 1;
    }

    // normalize + write O[s][h*128+d]
    #pragma unroll
    for (int r = 0; r < 4; ++r) {
      float inv = 1.f / l_r[r];
      long q = q0 + w * 16 + lg * 4 + r;
      #pragma unroll
      for (int df = 0; df < 8; ++df)
        O[q * HID + h * HD + df * 16 + lr] = __float2bfloat16(oacc[df][r] * inv);
    }
    __syncthreads();                        // phase boundary: lK/lV reuse
  }
}

// ---------- launcher ----------
extern "C" void kernel_launch(void* const* d_in, const int* in_sizes, int n_in,
                              void* d_out, int out_size, void* d_ws, size_t ws_size,
                              hipStream_t stream)
{
  (void)in_sizes; (void)n_in; (void)out_size;
  const float* hidden = (const float*)d_in[0];
  const int*   pos    = (const int*)d_in[1];
  const float* wqkv_w = (const float*)d_in[2];
  const float* wqkv_b = (const float*)d_in[3];
  const float* wo_w   = (const float*)d_in[4];
  const float* wo_b   = (const float*)d_in[5];
  float* out = (float*)d_out;

  // ws layout (bytes). Phase 1: hid_bf | wqkv_bf | qkv_bf.
  // Phase 2+ reuses hid_bf region as Qr, wqkv_bf region as Kr/Vt/Obf/Wo_bf/tables.
  char* ws = (char*)d_ws;
  if (ws_size < 167772160UL) return;        // need 160 MB
  __hip_bfloat16* hid_bf  = (__hip_bfloat16*)(ws + 0);          // 16 MB, later Qr
  __hip_bfloat16* wqkv_bf = (__hip_bfloat16*)(ws + 16777216);   // 96 MB
  __hip_bfloat16* qr      = (__hip_bfloat16*)(ws + 0);
  __hip_bfloat16* kr      = (__hip_bfloat16*)(ws + 16777216);
  __hip_bfloat16* vt      = (__hip_bfloat16*)(ws + 33554432);
  __hip_bfloat16* obf     = (__hip_bfloat16*)(ws + 50331648);
  __hip_bfloat16* wo_bf   = (__hip_bfloat16*)(ws + 67108864);   // 32 MB
  float*          cos_t   = (float*)(ws + 100663296);
  float*          sin_t   = (float*)(ws + 100663296 + 524288);
  __hip_bfloat16* qkv_bf  = (__hip_bfloat16*)(ws + 117440512);  // 48 MB -> total 160 MB

  cvt_bf16_kernel<<<4096, 256, 0, stream>>>(hidden, hid_bf, 8388608L);
  cvt_bf16_kernel<<<8192, 256, 0, stream>>>(wqkv_w, wqkv_bf, 50331648L);
  gemm_bt_kernel<1><<<dim3(16, 96), 256, 0, stream>>>(hid_bf, wqkv_bf, wqkv_b, qkv_bf, 2048, 12288, 4096);
  // safe to overwrite wqkv region only after the QKV GEMM
  cvt_bf16_kernel<<<8192, 256, 0, stream>>>(wo_w, wo_bf, 16777216L);
  rope_table_kernel<<<2048, 64, 0, stream>>>(pos, cos_t, sin_t);
  rope_rearrange_kernel<<<dim3(32, 32), 256, 0, stream>>>(qkv_bf, cos_t, sin_t, qr, kr, vt);
  flash_attn_kernel<<<dim3(16, 32), 256, 0, stream>>>(qr, kr, vt, obf);
  gemm_bt_kernel<0><<<dim3(16, 32), 256, 0, stream>>>(obf, wo_bf, wo_b, out, 2048, 4096, 4096);
}